// Round 10
// baseline (297.311 us; speedup 1.0000x reference)
//
#include <hip/hip_runtime.h>

// RGCN: bucketed atomic-free counting sort + FUSED gather-mean + bf16 MFMA GEMM.
//
//   seg(e) = rel(e)*nN + src(e)          (numSeg = nRel*nN)
//   out = sum_r mean_{e in seg(r,n)} x[dst_e,:] @ W_r^T + x @ root^T + bias
//
// Fused kernel: per 64-row block, per relation slab, gather-mean the 64
// segments straight into the LDS A-tile (16 lanes per segment, uint4 row
// loads, lane-local fp32 acc, pack bf16), then MFMA. As holds the FULL 128-k
// slab (round-9 bug: root-slab staging only filled 64 of 128 cols — fixed).

#define D 128
#define SCAN_CHUNK 2048
#define SEG_BITS 9
#define SEGS_PER_BUCKET 512
#define NBLK 128            // blocks for histA/scatterA
#define AP 136              // As pitch (bf16)
#define BP 72               // Bs pitch (bf16)

typedef __attribute__((ext_vector_type(8))) short short8;
typedef __attribute__((ext_vector_type(4))) float v4f;

__device__ __forceinline__ unsigned short f2b(float f) {
    union { float f; unsigned u; } v; v.f = f;
    unsigned r = v.u + 0x7fffu + ((v.u >> 16) & 1u);   // RNE
    return (unsigned short)(r >> 16);
}
__device__ __forceinline__ float blo(unsigned u) {
    union { unsigned u; float f; } v; v.u = u << 16; return v.f;
}
__device__ __forceinline__ float bhi(unsigned u) {
    union { unsigned u; float f; } v; v.u = u & 0xffff0000u; return v.f;
}

// ---------- fp32 -> bf16 bulk convert, three ranges in one launch ----------
__global__ void cvt_bf16_all(const float* __restrict__ x, long long nx,
                             const float* __restrict__ w, long long nw,
                             const float* __restrict__ root, long long nr,
                             unsigned short* __restrict__ xB,
                             unsigned short* __restrict__ wB) {
    long long i = ((long long)blockIdx.x * blockDim.x + threadIdx.x) * 4;
    const float* src;
    unsigned short* dst;
    long long j;
    if (i < nx) { src = x; dst = xB; j = i; }
    else if (i < nx + nw) { src = w; dst = wB; j = i - nx; }
    else if (i < nx + nw + nr) { src = root; dst = wB + nw; j = i - nx - nw; }
    else return;
    float4 v = *(const float4*)(src + j);
    uint2 p;
    p.x = (unsigned)f2b(v.x) | ((unsigned)f2b(v.y) << 16);
    p.y = (unsigned)f2b(v.z) | ((unsigned)f2b(v.w) << 16);
    *(uint2*)(dst + j) = p;
}

// ---------- phase A: per-block bucket histogram (LDS atomics only) ----------
__global__ __launch_bounds__(256)
void histA(const int* __restrict__ ei, const int* __restrict__ et,
           int* __restrict__ blockHist, int nE, int nN, int B, int epb) {
    __shared__ int lh[1024];
    const int tid = threadIdx.x;
    for (int b = tid; b < B; b += 256) lh[b] = 0;
    __syncthreads();
    const int base = blockIdx.x * epb;
    const int lim = min(base + epb, nE);
    for (int e = base + tid; e < lim; e += 256) {
        int seg = et[e] * nN + ei[e];
        atomicAdd(&lh[seg >> SEG_BITS], 1);
    }
    __syncthreads();
    for (int b = tid; b < B; b += 256)
        blockHist[b * NBLK + blockIdx.x] = lh[b];
}

// ---------- scan of blockHist (bucket-major), 3 kernels ----------
__global__ __launch_bounds__(256)
void scan1(const int* __restrict__ in, int* __restrict__ excl,
           int* __restrict__ blockSums, int n) {
    __shared__ int t[256];
    const int tid = threadIdx.x;
    const int base = blockIdx.x * SCAN_CHUNK + tid * 8;
    int v[8];
    int tot = 0;
#pragma unroll
    for (int i = 0; i < 8; i++) {
        v[i] = (base + i < n) ? in[base + i] : 0;
        tot += v[i];
    }
    t[tid] = tot;
    __syncthreads();
    for (int off = 1; off < 256; off <<= 1) {
        int add = (tid >= off) ? t[tid - off] : 0;
        __syncthreads();
        t[tid] += add;
        __syncthreads();
    }
    int run = t[tid] - tot;
#pragma unroll
    for (int i = 0; i < 8; i++) {
        if (base + i < n) excl[base + i] = run;
        run += v[i];
    }
    if (tid == 255) blockSums[blockIdx.x] = t[255];
}

__global__ __launch_bounds__(256)
void scan2(int* __restrict__ blockSums, int nb) {
    __shared__ int t[256];
    const int tid = threadIdx.x;
    int v = (tid < nb) ? blockSums[tid] : 0;
    t[tid] = v;
    __syncthreads();
    for (int off = 1; off < 256; off <<= 1) {
        int add = (tid >= off) ? t[tid - off] : 0;
        __syncthreads();
        t[tid] += add;
        __syncthreads();
    }
    if (tid < nb) blockSums[tid] = t[tid] - v;
}

__global__ __launch_bounds__(256)
void scan3s(int* __restrict__ excl, const int* __restrict__ blockSums, int n) {
    const int base = blockIdx.x * SCAN_CHUNK + threadIdx.x * 8;
    const int bs = blockSums[blockIdx.x];
#pragma unroll
    for (int i = 0; i < 8; i++)
        if (base + i < n) excl[base + i] += bs;
}

// ---------- phase C: bucket scatter (LDS cursors, packed 4B payload) ----------
__global__ __launch_bounds__(256)
void scatterA(const int* __restrict__ ei, const int* __restrict__ et,
              const int* __restrict__ scanned, unsigned* __restrict__ bucketEdges,
              int nE, int nN, int B, int epb) {
    __shared__ int cur[1024];
    const int tid = threadIdx.x;
    for (int b = tid; b < B; b += 256) cur[b] = scanned[b * NBLK + blockIdx.x];
    __syncthreads();
    const int base = blockIdx.x * epb;
    const int lim = min(base + epb, nE);
    for (int e = base + tid; e < lim; e += 256) {
        int seg = et[e] * nN + ei[e];
        int bkt = seg >> SEG_BITS;
        unsigned pk = ((unsigned)(seg & (SEGS_PER_BUCKET - 1)) << 16) | (unsigned)ei[nE + e];
        int pos = atomicAdd(&cur[bkt], 1);
        bucketEdges[pos] = pk;
    }
}

// ---------- phase D: per-bucket seg offsets + sorted ushort dst ----------
__global__ __launch_bounds__(256)
void segOff(const unsigned* __restrict__ bucketEdges, const int* __restrict__ scanned,
            int* __restrict__ off, unsigned short* __restrict__ sortedDst,
            int nE, int numSeg, int B) {
    __shared__ int lh[SEGS_PER_BUCKET];
    __shared__ int sc[256];
    __shared__ int lcur[SEGS_PER_BUCKET];
    const int tid = threadIdx.x;
    const int b = blockIdx.x;
    const int eBase = scanned[b * NBLK];
    const int eEnd = (b + 1 < B) ? scanned[(b + 1) * NBLK] : nE;
    const int segBase = b * SEGS_PER_BUCKET;
    const int segLim = min(SEGS_PER_BUCKET, numSeg - segBase);

    lh[2 * tid] = 0; lh[2 * tid + 1] = 0;
    __syncthreads();
    for (int i = eBase + tid; i < eEnd; i += 256)
        atomicAdd(&lh[bucketEdges[i] >> 16], 1);
    __syncthreads();
    int a0 = lh[2 * tid], a1 = lh[2 * tid + 1];
    sc[tid] = a0 + a1;
    __syncthreads();
    for (int o = 1; o < 256; o <<= 1) {
        int add = (tid >= o) ? sc[tid - o] : 0;
        __syncthreads();
        sc[tid] += add;
        __syncthreads();
    }
    int pairBase = sc[tid] - (a0 + a1);
    int g0 = eBase + pairBase;
    int g1 = g0 + a0;
    lcur[2 * tid] = g0;
    lcur[2 * tid + 1] = g1;
    if (2 * tid < segLim)     off[segBase + 2 * tid] = g0;
    if (2 * tid + 1 < segLim) off[segBase + 2 * tid + 1] = g1;
    if (b == B - 1 && tid == 0) off[numSeg] = nE;
    __syncthreads();
    for (int i = eBase + tid; i < eEnd; i += 256) {
        unsigned u = bucketEdges[i];
        int pos = atomicAdd(&lcur[u >> 16], 1);
        sortedDst[pos] = (unsigned short)(u & 0xFFFFu);
    }
}

// ---------- fused gather + MFMA GEMM ----------
// Block = 256 thr = 4 waves; out tile 64 rows x 128 cols.
// Per slab s<nRel: each wave gathers 16 segments (4 iters x 4 groups of 16
// lanes) straight into As (full 128 k); s==nRel copies full xB rows. Then per
// 64-k half: stage Bs from wB, MFMA 16x16x32.
__global__ __launch_bounds__(256, 4)
void rgcn_fused_mfma(const unsigned short* __restrict__ xB,
                     const unsigned short* __restrict__ sortedDst,
                     const int* __restrict__ off,
                     const unsigned short* __restrict__ wB,   // [nRel+1][128][128]
                     const float* __restrict__ bias,
                     float* __restrict__ out, int nN, int nRel) {
    __shared__ __align__(16) unsigned short As[64 * AP];
    __shared__ __align__(16) unsigned short Bs[128 * BP];
    const int tid = threadIdx.x;
    const int wv = tid >> 6;
    const int lane = tid & 63;
    const int idx16 = lane & 15;
    const int grp = lane >> 4;
    const int wm = wv & 1;
    const int wn = wv >> 1;
    const int m16 = lane & 15;
    const int q = lane >> 4;
    const int row0 = blockIdx.x * 64;

    v4f acc[2][4];
#pragma unroll
    for (int i = 0; i < 2; i++)
#pragma unroll
        for (int j = 0; j < 4; j++) acc[i][j] = (v4f){0.f, 0.f, 0.f, 0.f};

    const unsigned short* xChunk = xB + idx16 * 8;

    for (int s = 0; s <= nRel; s++) {
        __syncthreads();   // previous slab's MFMA done reading As
        if (s < nRel) {
            // gather-mean 64 segments into As (full 128 cols per row)
#pragma unroll 1
            for (int it = 0; it < 4; it++) {
                const int arow = wv * 16 + it * 4 + grp;
                const int n = row0 + arow;
                const bool valid = (n < nN);
                const int seg = valid ? (s * nN + n) : 0;
                const int start = off[seg];
                int cnt = valid ? (off[seg + 1] - start) : 0;
                int mx = cnt;
                mx = max(mx, __shfl_xor(mx, 16));
                mx = max(mx, __shfl_xor(mx, 32));
                float2 acc2[4];
#pragma unroll
                for (int i = 0; i < 4; i++) acc2[i] = make_float2(0.f, 0.f);
                for (int b = 0; b < mx; b += 16) {
                    int myDst = (b + idx16 < cnt) ? (int)sortedDst[start + b + idx16] : 0;
                    int kcap = min(16, mx - b);
                    for (int k = 0; k < kcap; k++) {
                        int dst = __shfl(myDst, grp * 16 + k);
                        if (b + k < cnt) {
                            uint4 v = *(const uint4*)(xChunk + ((size_t)dst << 7));
                            acc2[0].x += blo(v.x); acc2[0].y += bhi(v.x);
                            acc2[1].x += blo(v.y); acc2[1].y += bhi(v.y);
                            acc2[2].x += blo(v.z); acc2[2].y += bhi(v.z);
                            acc2[3].x += blo(v.w); acc2[3].y += bhi(v.w);
                        }
                    }
                }
                float sc = cnt > 0 ? 1.0f / (float)cnt : 0.f;
                uint4 pkt;
                pkt.x = (unsigned)f2b(acc2[0].x * sc) | ((unsigned)f2b(acc2[0].y * sc) << 16);
                pkt.y = (unsigned)f2b(acc2[1].x * sc) | ((unsigned)f2b(acc2[1].y * sc) << 16);
                pkt.z = (unsigned)f2b(acc2[2].x * sc) | ((unsigned)f2b(acc2[2].y * sc) << 16);
                pkt.w = (unsigned)f2b(acc2[3].x * sc) | ((unsigned)f2b(acc2[3].y * sc) << 16);
                *(uint4*)&As[arow * AP + idx16 * 8] = pkt;
            }
        } else {
            // root slab: copy FULL xB rows (128 cols = 16 chunks of 8 bf16)
#pragma unroll
            for (int p2 = 0; p2 < 4; p2++) {
                int idx = tid + p2 * 256;    // 0..1023
                int arow = idx >> 4;         // 0..63
                int ch = idx & 15;           // 0..15
                int n = row0 + arow;
                uint4 v = make_uint4(0u, 0u, 0u, 0u);
                if (n < nN)
                    v = *(const uint4*)(xB + (size_t)n * D + ch * 8);
                *(uint4*)&As[arow * AP + ch * 8] = v;
            }
        }

        const unsigned short* bSrc = wB + (size_t)s * D * D;
        for (int h = 0; h < 2; h++) {
            const int dbase = h * 64;
            __syncthreads();   // As ready (h=0); previous h's MFMA done w/ Bs
#pragma unroll
            for (int p2 = 0; p2 < 4; p2++) {
                int idx = tid + p2 * 256;
                int o = idx >> 3;
                int ch = idx & 7;
                uint4 v = *(const uint4*)(bSrc + (size_t)o * D + dbase + ch * 8);
                *(uint4*)&Bs[o * BP + ch * 8] = v;
            }
            __syncthreads();

#pragma unroll
            for (int kb = 0; kb < 64; kb += 32) {
                short8 a[2], b[4];
#pragma unroll
                for (int mt = 0; mt < 2; mt++)
                    a[mt] = *(const short8*)&As[(wm * 32 + mt * 16 + m16) * AP + dbase + kb + q * 8];
#pragma unroll
                for (int nt = 0; nt < 4; nt++)
                    b[nt] = *(const short8*)&Bs[(wn * 64 + nt * 16 + m16) * BP + kb + q * 8];
#pragma unroll
                for (int mt = 0; mt < 2; mt++)
#pragma unroll
                    for (int nt = 0; nt < 4; nt++)
                        acc[mt][nt] = __builtin_amdgcn_mfma_f32_16x16x32_bf16(
                            a[mt], b[nt], acc[mt][nt], 0, 0, 0);
            }
        }
    }

#pragma unroll
    for (int mt = 0; mt < 2; mt++) {
#pragma unroll
        for (int nt = 0; nt < 4; nt++) {
            int col = wn * 64 + nt * 16 + m16;
            float bi = bias[col];
#pragma unroll
            for (int reg = 0; reg < 4; reg++) {
                int rrow = row0 + wm * 32 + mt * 16 + q * 4 + reg;
                if (rrow < nN)
                    out[(size_t)rrow * D + col] = acc[mt][nt][reg] + bi;
            }
        }
    }
}

extern "C" void kernel_launch(void* const* d_in, const int* in_sizes, int n_in,
                              void* d_out, int out_size, void* d_ws, size_t ws_size,
                              hipStream_t stream) {
    const float* x    = (const float*)d_in[0];
    const int*   ei   = (const int*)d_in[1];
    const int*   et   = (const int*)d_in[2];
    const float* w    = (const float*)d_in[3];
    const float* root = (const float*)d_in[4];
    const float* bias = (const float*)d_in[5];
    float* out = (float*)d_out;

    const int nN   = in_sizes[0] / D;        // 50000 (< 65536 for ushort dst)
    const int nE   = in_sizes[2];
    const int nRel = in_sizes[3] / (D * D);
    const int numSeg = nRel * nN;
    const int B = (numSeg + SEGS_PER_BUCKET - 1) >> SEG_BITS;   // 782 (<= 1024)
    const int nBH = B * NBLK;
    const int epb = (nE + NBLK - 1) / NBLK;

    // workspace layout (~28 MB)
    char* p = (char*)d_ws;
    unsigned* bucketEdges   = (unsigned*)p;        p += (size_t)nE * sizeof(unsigned);
    unsigned short* sortedDst = (unsigned short*)p; p += (size_t)nE * sizeof(unsigned short);
    p = (char*)(((uintptr_t)p + 255) & ~(uintptr_t)255);
    int* off       = (int*)p;  p += (size_t)(numSeg + 1) * sizeof(int);
    int* blockHist = (int*)p;  p += (size_t)nBH * sizeof(int);
    int* scanned   = (int*)p;  p += (size_t)nBH * sizeof(int);
    int* blockSums = (int*)p;  p += 256 * sizeof(int);
    p = (char*)(((uintptr_t)p + 255) & ~(uintptr_t)255);
    unsigned short* xB   = (unsigned short*)p;  p += (size_t)nN * D * sizeof(unsigned short);
    unsigned short* wB   = (unsigned short*)p;  p += (size_t)(nRel + 1) * D * D * sizeof(unsigned short);

    const int nScanBlocks = (nBH + SCAN_CHUNK - 1) / SCAN_CHUNK;  // 49 <= 256

    histA<<<NBLK, 256, 0, stream>>>(ei, et, blockHist, nE, nN, B, epb);
    scan1<<<nScanBlocks, 256, 0, stream>>>(blockHist, scanned, blockSums, nBH);
    scan2<<<1, 256, 0, stream>>>(blockSums, nScanBlocks);
    scan3s<<<nScanBlocks, 256, 0, stream>>>(scanned, blockSums, nBH);
    scatterA<<<NBLK, 256, 0, stream>>>(ei, et, scanned, bucketEdges, nE, nN, B, epb);
    segOff<<<B, 256, 0, stream>>>(bucketEdges, scanned, off, sortedDst, nE, numSeg, B);

    long long nx = (long long)nN * D;
    long long nw = (long long)nRel * D * D;
    long long nr = (long long)D * D;
    long long ncvt = (nx + nw + nr) / 4;
    cvt_bf16_all<<<(int)((ncvt + 255) / 256), 256, 0, stream>>>(x, nx, w, nw, root, nr, xB, wB);

    rgcn_fused_mfma<<<(nN + 63) / 64, 256, 0, stream>>>(xB, sortedDst, off, wB, bias,
                                                        out, nN, nRel);
}

// Round 11
// 262.988 us; speedup vs baseline: 1.1305x; 1.1305x over previous
//
#include <hip/hip_runtime.h>

// RGCN: bucketed atomic-free counting sort + bf16 gather (4-load MLP batching,
// lane-local acc, nt store) + bf16 MFMA GEMM.  (Round-10 fusion regressed:
// gather needs TLP; keep split structure.)
//
//   seg(e) = rel(e)*nN + src(e)          (numSeg = nRel*nN)
//   aggB[seg,:] = bf16( mean_{e in seg} x[dst_e,:] )
//   out = sum_r aggB_r @ W_r^T + x @ root^T + bias   (MFMA 16x16x32 bf16)

#define D 128
#define SCAN_CHUNK 2048
#define SEG_BITS 9
#define SEGS_PER_BUCKET 512
#define NBLK 128            // blocks for histA/scatterA
#define APITCH 72

typedef __attribute__((ext_vector_type(8))) short short8;
typedef __attribute__((ext_vector_type(4))) float v4f;
typedef __attribute__((ext_vector_type(4))) unsigned uint4v;

__device__ __forceinline__ unsigned short f2b(float f) {
    union { float f; unsigned u; } v; v.f = f;
    unsigned r = v.u + 0x7fffu + ((v.u >> 16) & 1u);   // RNE
    return (unsigned short)(r >> 16);
}
__device__ __forceinline__ float blo(unsigned u) {
    union { unsigned u; float f; } v; v.u = u << 16; return v.f;
}
__device__ __forceinline__ float bhi(unsigned u) {
    union { unsigned u; float f; } v; v.u = u & 0xffff0000u; return v.f;
}

// ---------- fp32 -> bf16 bulk convert, three ranges in one launch ----------
__global__ void cvt_bf16_all(const float* __restrict__ x, long long nx,
                             const float* __restrict__ w, long long nw,
                             const float* __restrict__ root, long long nr,
                             unsigned short* __restrict__ xB,
                             unsigned short* __restrict__ wB) {
    long long i = ((long long)blockIdx.x * blockDim.x + threadIdx.x) * 4;
    const float* src;
    unsigned short* dst;
    long long j;
    if (i < nx) { src = x; dst = xB; j = i; }
    else if (i < nx + nw) { src = w; dst = wB; j = i - nx; }
    else if (i < nx + nw + nr) { src = root; dst = wB + nw; j = i - nx - nw; }
    else return;
    float4 v = *(const float4*)(src + j);
    uint2 p;
    p.x = (unsigned)f2b(v.x) | ((unsigned)f2b(v.y) << 16);
    p.y = (unsigned)f2b(v.z) | ((unsigned)f2b(v.w) << 16);
    *(uint2*)(dst + j) = p;
}

// ---------- phase A: per-block bucket histogram (LDS atomics only) ----------
__global__ __launch_bounds__(256)
void histA(const int* __restrict__ ei, const int* __restrict__ et,
           int* __restrict__ blockHist, int nE, int nN, int B, int epb) {
    __shared__ int lh[1024];
    const int tid = threadIdx.x;
    for (int b = tid; b < B; b += 256) lh[b] = 0;
    __syncthreads();
    const int base = blockIdx.x * epb;
    const int lim = min(base + epb, nE);
    for (int e = base + tid; e < lim; e += 256) {
        int seg = et[e] * nN + ei[e];
        atomicAdd(&lh[seg >> SEG_BITS], 1);
    }
    __syncthreads();
    for (int b = tid; b < B; b += 256)
        blockHist[b * NBLK + blockIdx.x] = lh[b];
}

// ---------- scan of blockHist (bucket-major), 3 kernels ----------
__global__ __launch_bounds__(256)
void scan1(const int* __restrict__ in, int* __restrict__ excl,
           int* __restrict__ blockSums, int n) {
    __shared__ int t[256];
    const int tid = threadIdx.x;
    const int base = blockIdx.x * SCAN_CHUNK + tid * 8;
    int v[8];
    int tot = 0;
#pragma unroll
    for (int i = 0; i < 8; i++) {
        v[i] = (base + i < n) ? in[base + i] : 0;
        tot += v[i];
    }
    t[tid] = tot;
    __syncthreads();
    for (int off = 1; off < 256; off <<= 1) {
        int add = (tid >= off) ? t[tid - off] : 0;
        __syncthreads();
        t[tid] += add;
        __syncthreads();
    }
    int run = t[tid] - tot;
#pragma unroll
    for (int i = 0; i < 8; i++) {
        if (base + i < n) excl[base + i] = run;
        run += v[i];
    }
    if (tid == 255) blockSums[blockIdx.x] = t[255];
}

__global__ __launch_bounds__(256)
void scan2(int* __restrict__ blockSums, int nb) {
    __shared__ int t[256];
    const int tid = threadIdx.x;
    int v = (tid < nb) ? blockSums[tid] : 0;
    t[tid] = v;
    __syncthreads();
    for (int off = 1; off < 256; off <<= 1) {
        int add = (tid >= off) ? t[tid - off] : 0;
        __syncthreads();
        t[tid] += add;
        __syncthreads();
    }
    if (tid < nb) blockSums[tid] = t[tid] - v;
}

__global__ __launch_bounds__(256)
void scan3s(int* __restrict__ excl, const int* __restrict__ blockSums, int n) {
    const int base = blockIdx.x * SCAN_CHUNK + threadIdx.x * 8;
    const int bs = blockSums[blockIdx.x];
#pragma unroll
    for (int i = 0; i < 8; i++)
        if (base + i < n) excl[base + i] += bs;
}

// ---------- phase C: bucket scatter (LDS cursors, packed 4B payload) ----------
__global__ __launch_bounds__(256)
void scatterA(const int* __restrict__ ei, const int* __restrict__ et,
              const int* __restrict__ scanned, unsigned* __restrict__ bucketEdges,
              int nE, int nN, int B, int epb) {
    __shared__ int cur[1024];
    const int tid = threadIdx.x;
    for (int b = tid; b < B; b += 256) cur[b] = scanned[b * NBLK + blockIdx.x];
    __syncthreads();
    const int base = blockIdx.x * epb;
    const int lim = min(base + epb, nE);
    for (int e = base + tid; e < lim; e += 256) {
        int seg = et[e] * nN + ei[e];
        int bkt = seg >> SEG_BITS;
        unsigned pk = ((unsigned)(seg & (SEGS_PER_BUCKET - 1)) << 16) | (unsigned)ei[nE + e];
        int pos = atomicAdd(&cur[bkt], 1);
        bucketEdges[pos] = pk;
    }
}

// ---------- phase D: per-bucket seg offsets + sorted ushort dst ----------
__global__ __launch_bounds__(256)
void segOff(const unsigned* __restrict__ bucketEdges, const int* __restrict__ scanned,
            int* __restrict__ off, unsigned short* __restrict__ sortedDst,
            int nE, int numSeg, int B) {
    __shared__ int lh[SEGS_PER_BUCKET];
    __shared__ int sc[256];
    __shared__ int lcur[SEGS_PER_BUCKET];
    const int tid = threadIdx.x;
    const int b = blockIdx.x;
    const int eBase = scanned[b * NBLK];
    const int eEnd = (b + 1 < B) ? scanned[(b + 1) * NBLK] : nE;
    const int segBase = b * SEGS_PER_BUCKET;
    const int segLim = min(SEGS_PER_BUCKET, numSeg - segBase);

    lh[2 * tid] = 0; lh[2 * tid + 1] = 0;
    __syncthreads();
    for (int i = eBase + tid; i < eEnd; i += 256)
        atomicAdd(&lh[bucketEdges[i] >> 16], 1);
    __syncthreads();
    int a0 = lh[2 * tid], a1 = lh[2 * tid + 1];
    sc[tid] = a0 + a1;
    __syncthreads();
    for (int o = 1; o < 256; o <<= 1) {
        int add = (tid >= o) ? sc[tid - o] : 0;
        __syncthreads();
        sc[tid] += add;
        __syncthreads();
    }
    int pairBase = sc[tid] - (a0 + a1);
    int g0 = eBase + pairBase;
    int g1 = g0 + a0;
    lcur[2 * tid] = g0;
    lcur[2 * tid + 1] = g1;
    if (2 * tid < segLim)     off[segBase + 2 * tid] = g0;
    if (2 * tid + 1 < segLim) off[segBase + 2 * tid + 1] = g1;
    if (b == B - 1 && tid == 0) off[numSeg] = nE;
    __syncthreads();
    for (int i = eBase + tid; i < eEnd; i += 256) {
        unsigned u = bucketEdges[i];
        int pos = atomicAdd(&lcur[u >> 16], 1);
        sortedDst[pos] = (unsigned short)(u & 0xFFFFu);
    }
}

// ---------- gather: 4 segments/wave, 16 lanes/segment, 4-edge load batching ----
__global__ __launch_bounds__(256)
void rgcn_gather(const unsigned short* __restrict__ xB,
                 const unsigned short* __restrict__ sortedDst,
                 const int* __restrict__ off,
                 unsigned short* __restrict__ aggB, int nN) {
    const int tid = threadIdx.x;
    const int lane = tid & 63;
    const int idx16 = lane & 15;
    const int grp = lane >> 4;
    const int wv = tid >> 6;
    const int n = blockIdx.x * 16 + wv * 4 + grp;
    const int r = blockIdx.y;
    const bool valid = (n < nN);
    const int seg = valid ? (r * nN + n) : 0;

    const int start = off[seg];
    int cnt = valid ? (off[seg + 1] - start) : 0;

    int mx = cnt;
    mx = max(mx, __shfl_xor(mx, 16));
    mx = max(mx, __shfl_xor(mx, 32));

    float2 acc2[4];
#pragma unroll
    for (int i = 0; i < 4; i++) acc2[i] = make_float2(0.f, 0.f);

    const unsigned short* xChunk = xB + idx16 * 8;

    for (int b = 0; b < mx; b += 16) {
        int myDst = (b + idx16 < cnt) ? (int)sortedDst[start + b + idx16] : 0;
        int kcap = min(16, mx - b);
        for (int g = 0; g < kcap; g += 4) {
            // batch 4 independent predicated loads (act uniform per 16-lane grp)
            uint4v v[4];
#pragma unroll
            for (int j = 0; j < 4; j++) {
                int k = g + j;
                int dst = __shfl(myDst, grp * 16 + k);
                bool act = (k < kcap) && (b + k < cnt);
                v[j] = act ? *(const uint4v*)(xChunk + ((size_t)dst << 7))
                           : (uint4v){0u, 0u, 0u, 0u};
            }
#pragma unroll
            for (int j = 0; j < 4; j++) {
                acc2[0].x += blo(v[j].x); acc2[0].y += bhi(v[j].x);
                acc2[1].x += blo(v[j].y); acc2[1].y += bhi(v[j].y);
                acc2[2].x += blo(v[j].z); acc2[2].y += bhi(v[j].z);
                acc2[3].x += blo(v[j].w); acc2[3].y += bhi(v[j].w);
            }
        }
    }

    if (valid) {
        float s = cnt > 0 ? 1.0f / (float)cnt : 0.f;
        uint4v pkt;
        pkt.x = (unsigned)f2b(acc2[0].x * s) | ((unsigned)f2b(acc2[0].y * s) << 16);
        pkt.y = (unsigned)f2b(acc2[1].x * s) | ((unsigned)f2b(acc2[1].y * s) << 16);
        pkt.z = (unsigned)f2b(acc2[2].x * s) | ((unsigned)f2b(acc2[2].y * s) << 16);
        pkt.w = (unsigned)f2b(acc2[3].x * s) | ((unsigned)f2b(acc2[3].y * s) << 16);
        // nt store: aggB not re-read until the GEMM; keep xB resident in L2
        __builtin_nontemporal_store(pkt, (uint4v*)(aggB + (size_t)seg * D + idx16 * 8));
    }
}

// ---------- MFMA GEMM: M=nN, N=128, K=9*128; A = [agg slabs | xB], B = wB ----------
__global__ __launch_bounds__(256)
void rgcn_gemm_mfma(const unsigned short* __restrict__ aggB,
                    const unsigned short* __restrict__ xB,
                    const unsigned short* __restrict__ wB,   // [nRel+1][128][128]
                    const float* __restrict__ bias,
                    float* __restrict__ out, int nN, int nRel) {
    __shared__ __align__(16) unsigned short As[64 * APITCH];
    __shared__ __align__(16) unsigned short Bs[128 * APITCH];
    const int tid = threadIdx.x;
    const int wave = tid >> 6;
    const int lane = tid & 63;
    const int wm = wave & 1;
    const int wn = wave >> 1;
    const int m16 = lane & 15;
    const int q = lane >> 4;
    const int row0 = blockIdx.x * 64;

    v4f acc[2][4];
#pragma unroll
    for (int i = 0; i < 2; i++)
#pragma unroll
        for (int j = 0; j < 4; j++) acc[i][j] = (v4f){0.f, 0.f, 0.f, 0.f};

    const int nSlabs = nRel + 1;
    for (int s = 0; s < nSlabs; s++) {
        const unsigned short* aSrc = (s < nRel) ? (aggB + (size_t)s * nN * D) : xB;
        const unsigned short* bSrc = wB + (size_t)s * D * D;
        for (int h = 0; h < 2; h++) {
            const int dbase = h * 64;
#pragma unroll
            for (int p = 0; p < 2; p++) {
                int idx = tid + p * 256;
                int arow = idx >> 3;
                int ch = idx & 7;
                int n = row0 + arow;
                uint4 v = make_uint4(0u, 0u, 0u, 0u);
                if (n < nN)
                    v = *(const uint4*)(aSrc + (size_t)n * D + dbase + ch * 8);
                *(uint4*)&As[arow * APITCH + ch * 8] = v;
            }
#pragma unroll
            for (int p = 0; p < 4; p++) {
                int idx = tid + p * 256;
                int o = idx >> 3;
                int ch = idx & 7;
                uint4 v = *(const uint4*)(bSrc + (size_t)o * D + dbase + ch * 8);
                *(uint4*)&Bs[o * APITCH + ch * 8] = v;
            }
            __syncthreads();

#pragma unroll
            for (int kb = 0; kb < 64; kb += 32) {
                short8 a[2], b[4];
#pragma unroll
                for (int mt = 0; mt < 2; mt++)
                    a[mt] = *(const short8*)&As[(wm * 32 + mt * 16 + m16) * APITCH + kb + q * 8];
#pragma unroll
                for (int nt = 0; nt < 4; nt++)
                    b[nt] = *(const short8*)&Bs[(wn * 64 + nt * 16 + m16) * APITCH + kb + q * 8];
#pragma unroll
                for (int mt = 0; mt < 2; mt++)
#pragma unroll
                    for (int nt = 0; nt < 4; nt++)
                        acc[mt][nt] = __builtin_amdgcn_mfma_f32_16x16x32_bf16(
                            a[mt], b[nt], acc[mt][nt], 0, 0, 0);
            }
            __syncthreads();
        }
    }

#pragma unroll
    for (int mt = 0; mt < 2; mt++) {
#pragma unroll
        for (int nt = 0; nt < 4; nt++) {
            int col = wn * 64 + nt * 16 + m16;
            float bi = bias[col];
#pragma unroll
            for (int reg = 0; reg < 4; reg++) {
                int rrow = row0 + wm * 32 + mt * 16 + q * 4 + reg;
                if (rrow < nN)
                    out[(size_t)rrow * D + col] = acc[mt][nt][reg] + bi;
            }
        }
    }
}

extern "C" void kernel_launch(void* const* d_in, const int* in_sizes, int n_in,
                              void* d_out, int out_size, void* d_ws, size_t ws_size,
                              hipStream_t stream) {
    const float* x    = (const float*)d_in[0];
    const int*   ei   = (const int*)d_in[1];
    const int*   et   = (const int*)d_in[2];
    const float* w    = (const float*)d_in[3];
    const float* root = (const float*)d_in[4];
    const float* bias = (const float*)d_in[5];
    float* out = (float*)d_out;

    const int nN   = in_sizes[0] / D;        // 50000 (< 65536 for ushort dst)
    const int nE   = in_sizes[2];
    const int nRel = in_sizes[3] / (D * D);
    const int numSeg = nRel * nN;
    const int B = (numSeg + SEGS_PER_BUCKET - 1) >> SEG_BITS;   // 782 (<= 1024)
    const int nBH = B * NBLK;
    const int epb = (nE + NBLK - 1) / NBLK;

    // workspace layout (~130 MB; ws proven >= 218 MB in round 4)
    char* p = (char*)d_ws;
    unsigned* bucketEdges   = (unsigned*)p;        p += (size_t)nE * sizeof(unsigned);
    unsigned short* sortedDst = (unsigned short*)p; p += (size_t)nE * sizeof(unsigned short);
    p = (char*)(((uintptr_t)p + 255) & ~(uintptr_t)255);
    int* off       = (int*)p;  p += (size_t)(numSeg + 1) * sizeof(int);
    int* blockHist = (int*)p;  p += (size_t)nBH * sizeof(int);
    int* scanned   = (int*)p;  p += (size_t)nBH * sizeof(int);
    int* blockSums = (int*)p;  p += 256 * sizeof(int);
    p = (char*)(((uintptr_t)p + 255) & ~(uintptr_t)255);
    unsigned short* xB   = (unsigned short*)p;  p += (size_t)nN * D * sizeof(unsigned short);
    unsigned short* wB   = (unsigned short*)p;  p += (size_t)(nRel + 1) * D * D * sizeof(unsigned short);
    p = (char*)(((uintptr_t)p + 255) & ~(uintptr_t)255);
    unsigned short* aggB = (unsigned short*)p;

    const int nScanBlocks = (nBH + SCAN_CHUNK - 1) / SCAN_CHUNK;  // 49 <= 256

    histA<<<NBLK, 256, 0, stream>>>(ei, et, blockHist, nE, nN, B, epb);
    scan1<<<nScanBlocks, 256, 0, stream>>>(blockHist, scanned, blockSums, nBH);
    scan2<<<1, 256, 0, stream>>>(blockSums, nScanBlocks);
    scan3s<<<nScanBlocks, 256, 0, stream>>>(scanned, blockSums, nBH);
    scatterA<<<NBLK, 256, 0, stream>>>(ei, et, scanned, bucketEdges, nE, nN, B, epb);
    segOff<<<B, 256, 0, stream>>>(bucketEdges, scanned, off, sortedDst, nE, numSeg, B);

    long long nx = (long long)nN * D;
    long long nw = (long long)nRel * D * D;
    long long nr = (long long)D * D;
    long long ncvt = (nx + nw + nr) / 4;
    cvt_bf16_all<<<(int)((ncvt + 255) / 256), 256, 0, stream>>>(x, nx, w, nw, root, nr, xB, wB);

    dim3 gg((nN + 15) / 16, nRel);
    rgcn_gather<<<gg, 256, 0, stream>>>(xB, sortedDst, off, aggB, nN);

    rgcn_gemm_mfma<<<(nN + 63) / 64, 256, 0, stream>>>(aggB, xB, wB, bias, out, nN, nRel);
}